// Round 1
// baseline (794.730 us; speedup 1.0000x reference)
//
#include <hip/hip_runtime.h>

#define NB    96
#define HID   6144
#define INSZ  2048
#define FPB   21
#define OPB   21
#define OUTD  2016
#define BATCH 4096
#define NEG   0.01f

typedef _Float16 half8 __attribute__((ext_vector_type(8)));
typedef float floatx4 __attribute__((ext_vector_type(4)));

__device__ __forceinline__ unsigned short f2h_bits(float f) {
    union { _Float16 h; unsigned short u; } v;
    v.h = (_Float16)f;
    return v.u;
}

// ---------------------------------------------------------------------------
// Pack masked weights into FRAGMENT-MAJOR f16 layouts so each wave's 16B
// B-fragment load is one fully-coalesced 1KB transaction.
//  whpF: [3][96][kk=6][u=4][lane=64][j=8]   element (col=u*16+(lane&15),
//         k=kk*32+(lane>>4)*8+j) of the gathered [64][192] per-bus block
//  w0F : [96][u=4][lane=64][j=8]            k = (lane>>4)*8+j  (K=32)
//  woF : [96][kk=2][u=2][lane=64][j=8]      out-row=u*16+(lane&15), K=64
// ---------------------------------------------------------------------------
__global__ __launch_bounds__(256) void pack_weights(
    const float* __restrict__ W0, const float* __restrict__ W1,
    const float* __restrict__ W2, const float* __restrict__ W3,
    const float* __restrict__ Wo,
    unsigned short* __restrict__ whpF,
    unsigned short* __restrict__ w0F,
    unsigned short* __restrict__ woF)
{
    const int NH = 3 * NB * 12288;   // 3538944
    const int N0 = NB * 2048;        // 196608
    const int NO = NB * 2048;        // 196608
    int idx = blockIdx.x * 256 + threadIdx.x;
    if (idx < NH) {
        int e = idx;
        int l = e / 1179648;
        int r = e - l * 1179648;
        int bus = r / 12288;
        int r1 = r - bus * 12288;
        int kk = r1 >> 11;
        int r2 = r1 & 2047;
        int u = r2 >> 9;
        int r3 = r2 & 511;
        int lane = r3 >> 3, j = r3 & 7;
        int mq = lane & 15, q = lane >> 4;
        int col = u * 16 + mq;
        int k = kk * 32 + q * 8 + j;
        int src_b = (bus + 95 + (k >> 6)) % NB;
        const float* W = (l == 0) ? W1 : (l == 1) ? W2 : W3;
        float v = W[(size_t)(bus * 64 + col) * HID + src_b * 64 + (k & 63)];
        whpF[e] = f2h_bits(v);
    } else if (idx < NH + N0) {
        int e = idx - NH;
        int bus = e >> 11;
        int r = e & 2047;
        int u = r >> 9;
        int r2 = r & 511;
        int lane = r2 >> 3, j = r2 & 7;
        int mq = lane & 15, q = lane >> 4;
        int col = u * 16 + mq;
        int k = q * 8 + j;
        float v = 0.f;
        if (k < FPB)      v = W0[(size_t)(bus * 64 + col) * INSZ + bus * FPB + k];
        else if (k < 30)  v = W0[(size_t)(bus * 64 + col) * INSZ + (INSZ - 9) + (k - FPB)];
        w0F[e] = f2h_bits(v);
    } else if (idx < NH + N0 + NO) {
        int e = idx - NH - N0;
        int bus = e >> 11;
        int r = e & 2047;
        int kk = r >> 10;
        int r2 = r & 1023;
        int u = r2 >> 9;
        int r3 = r2 & 511;
        int lane = r3 >> 3, j = r3 & 7;
        int mq = lane & 15, q = lane >> 4;
        int row32 = u * 16 + mq;
        int k = kk * 32 + q * 8 + j;
        float v = 0.f;
        if (row32 < OPB)
            v = Wo[(size_t)(bus * OPB + row32) * HID + bus * 64 + k];
        woF[e] = f2h_bits(v);
    }
}

// ---------------------------------------------------------------------------
// Async A-chunk prefetch: 64 rows x 192 cols gathered into granule-swizzled
// LDS: granule g holds (row=g/24, kg=(g%24 - row%24) mod 24) -> compute reads
// land 2-way bank aliased (free). global_load_lds needs dest = uniform base +
// lane*16, which this satisfies by construction.
// ---------------------------------------------------------------------------
__device__ __forceinline__ void mid_prefetch(
    const unsigned short* __restrict__ hin, unsigned short* AsBuf,
    int tid, int gbase_row, int cb0, int cb1, int cb2)
{
    #pragma unroll
    for (int i = 0; i < 6; ++i) {
        int g = i * 256 + tid;
        int row = g / 24;
        int j = g - row * 24;
        int kg = j - (row % 24);
        kg += (kg < 0) ? 24 : 0;
        const unsigned short* src = hin + (size_t)(gbase_row + row) * HID
                                  + (kg < 8 ? cb0 : (kg < 16 ? cb1 : cb2)) + (kg & 7) * 8;
        __builtin_amdgcn_global_load_lds(
            (const __attribute__((address_space(1))) unsigned int*)src,
            (__attribute__((address_space(3))) unsigned int*)(AsBuf + (size_t)(i * 256 + (tid & ~63)) * 8),
            16, 0, 0);
    }
}

// ---------------------------------------------------------------------------
// Middle layers: per-bus GEMM M=4096,N=64,K=192. Block: 256 thr, M=256 in
// 4 chunks of 64 rows, double-buffered async staging. W frags in registers.
//
// XCD-aware remap (this round's change): with the natural mapping, bus is the
// fast dispatch dim, so buses b-1,b,b+1 — which all read the SAME 64-col
// activation block — land on 3 DIFFERENT (non-coherent) per-XCD L2s, and the
// 3x ring read amplification goes straight to HBM. Remap so XCD k owns buses
// [12k,12k+12) across all rowblks (bus-fastest): the shared column slices
// (14 blocks x ~8 live rowblk slices x 32KB ~= 3.6MB) then fit the 4MB
// per-XCD L2. 1536 % 8 == 0 -> the %8 swizzle is bijective.
// ---------------------------------------------------------------------------
__global__ __launch_bounds__(256) void mid_kernel(
    const unsigned short* __restrict__ hin,
    const unsigned short* __restrict__ WpF,   // fragment-major, this layer
    const float* __restrict__ bias,
    unsigned short* __restrict__ hout)
{
    __shared__ unsigned short AsF[2][1536 * 8];   // 2 x 24 KB
    const int lin = blockIdx.y * NB + blockIdx.x;   // linear dispatch id
    const int xcd = lin & 7;                        // round-robin XCD assignment
    const int idx = lin >> 3;                       // 0..191 within XCD
    const int bus = xcd * 12 + (idx % 12);          // XCD k owns buses [12k,12k+12)
    const int rowblk = (idx / 12) * 256;
    const int tid = threadIdx.x;
    const int lane = tid & 63, wid = tid >> 6;
    const int mq = lane & 15, q = lane >> 4;
    const int cb0 = ((bus + 95) % NB) * 64;
    const int cb1 = bus * 64;
    const int cb2 = ((bus + 1) % NB) * 64;

    half8 bfr[6][4];
    #pragma unroll
    for (int kk = 0; kk < 6; ++kk)
        #pragma unroll
        for (int u = 0; u < 4; ++u)
            bfr[kk][u] = *(const half8*)(WpF + (size_t)(((bus * 6 + kk) * 4 + u) * 512) + lane * 8);

    float bv[4];
    #pragma unroll
    for (int u = 0; u < 4; ++u) bv[u] = bias[bus * 64 + u * 16 + mq];

    mid_prefetch(hin, &AsF[0][0], tid, rowblk, cb0, cb1, cb2);
    __syncthreads();

    const int row = wid * 16 + mq;       // row within chunk, 0..63
    const int r24 = row % 24;
    const int qr = q + r24;

    for (int c = 0; c < 4; ++c) {
        int buf = c & 1;
        if (c < 3)
            mid_prefetch(hin, &AsF[buf ^ 1][0], tid, rowblk + (c + 1) * 64, cb0, cb1, cb2);

        floatx4 acc[4];
        #pragma unroll
        for (int u = 0; u < 4; ++u) acc[u] = (floatx4){0.f, 0.f, 0.f, 0.f};

        #pragma unroll
        for (int kk = 0; kk < 6; ++kk) {
            int vv = 4 * kk + qr;
            if (vv >= 24) vv -= 24;
            half8 a = *(const half8*)(&AsF[buf][(row * 24 + vv) * 8]);
            #pragma unroll
            for (int u = 0; u < 4; ++u)
                acc[u] = __builtin_amdgcn_mfma_f32_16x16x32_f16(a, bfr[kk][u], acc[u], 0, 0, 0);
        }

        int orow = rowblk + c * 64 + wid * 16 + q * 4;
        #pragma unroll
        for (int u = 0; u < 4; ++u) {
            int colg = bus * 64 + u * 16 + mq;
            #pragma unroll
            for (int r = 0; r < 4; ++r) {
                float v = acc[u][r] + bv[u];
                v = (v >= 0.f) ? v : NEG * v;
                hout[(size_t)(orow + r) * HID + colg] = f2h_bits(v);
            }
        }
        __syncthreads();
    }
}

// ---------------------------------------------------------------------------
// Layer 0: per-bus GEMM M=4096,N=64,K=32 (30 real). W frags in registers,
// LDS only for gathered f32->f16 A tile (10 KB -> high occupancy).
// ---------------------------------------------------------------------------
__global__ __launch_bounds__(256) void layer0_kernel(
    const float* __restrict__ x,
    const unsigned short* __restrict__ w0F,
    const float* __restrict__ b0,
    unsigned short* __restrict__ hout)
{
    __shared__ unsigned short As[128][40];
    int bus = blockIdx.x, rb = blockIdx.y * 128, tid = threadIdx.x;
    int lane = tid & 63, wid = tid >> 6, mq = lane & 15, q = lane >> 4;

    half8 b0f[4];
    #pragma unroll
    for (int u = 0; u < 4; ++u)
        b0f[u] = *(const half8*)(w0F + (size_t)(bus * 4 + u) * 512 + lane * 8);

    #pragma unroll
    for (int i = 0; i < 16; ++i) {
        int g = i * 256 + tid;
        int row = g >> 5, k = g & 31;
        float v = 0.f;
        if (k < FPB)      v = x[(size_t)(rb + row) * INSZ + bus * FPB + k];
        else if (k < 30)  v = x[(size_t)(rb + row) * INSZ + (INSZ - 9) + (k - FPB)];
        As[row][k] = f2h_bits(v);
    }
    __syncthreads();

    int m_base = wid * 32;
    floatx4 acc[2][4];
    #pragma unroll
    for (int t = 0; t < 2; ++t)
        #pragma unroll
        for (int u = 0; u < 4; ++u)
            acc[t][u] = (floatx4){0.f, 0.f, 0.f, 0.f};

    half8 a0 = *(const half8*)(&As[m_base + mq][q * 8]);
    half8 a1 = *(const half8*)(&As[m_base + 16 + mq][q * 8]);
    #pragma unroll
    for (int u = 0; u < 4; ++u) {
        acc[0][u] = __builtin_amdgcn_mfma_f32_16x16x32_f16(a0, b0f[u], acc[0][u], 0, 0, 0);
        acc[1][u] = __builtin_amdgcn_mfma_f32_16x16x32_f16(a1, b0f[u], acc[1][u], 0, 0, 0);
    }

    #pragma unroll
    for (int t = 0; t < 2; ++t)
        #pragma unroll
        for (int u = 0; u < 4; ++u) {
            int col = bus * 64 + u * 16 + mq;
            float bvv = b0[col];
            #pragma unroll
            for (int r = 0; r < 4; ++r) {
                int rowg = rb + m_base + t * 16 + q * 4 + r;
                float v = acc[t][u][r] + bvv;
                v = (v >= 0.f) ? v : NEG * v;
                hout[(size_t)rowg * HID + col] = f2h_bits(v);
            }
        }
}

// ---------------------------------------------------------------------------
// Output layer: per-bus GEMM M=4096,N=21(pad 32),K=64. f32 out, no ReLU.
// ---------------------------------------------------------------------------
__global__ __launch_bounds__(256) void out_kernel(
    const unsigned short* __restrict__ hin,
    const unsigned short* __restrict__ woF,
    const float* __restrict__ bo,
    float* __restrict__ out)
{
    __shared__ unsigned short As[128][72];
    int bus = blockIdx.x, rb = blockIdx.y * 128, tid = threadIdx.x;
    int lane = tid & 63, wid = tid >> 6, mq = lane & 15, q = lane >> 4;

    half8 wf[2][2];
    #pragma unroll
    for (int kk = 0; kk < 2; ++kk)
        #pragma unroll
        for (int u = 0; u < 2; ++u)
            wf[kk][u] = *(const half8*)(woF + (size_t)(((bus * 2 + kk) * 2 + u) * 512) + lane * 8);

    #pragma unroll
    for (int i = 0; i < 4; ++i) {
        int g = i * 256 + tid;
        int row = g >> 3, kg = g & 7;
        *(uint4*)(&As[row][kg * 8]) =
            *(const uint4*)(hin + (size_t)(rb + row) * HID + bus * 64 + kg * 8);
    }
    __syncthreads();

    int m_base = wid * 32;
    floatx4 acc[2][2];
    #pragma unroll
    for (int t = 0; t < 2; ++t)
        #pragma unroll
        for (int u = 0; u < 2; ++u)
            acc[t][u] = (floatx4){0.f, 0.f, 0.f, 0.f};

    #pragma unroll
    for (int kk = 0; kk < 2; ++kk) {
        int ko = kk * 32 + q * 8;
        half8 a0 = *(const half8*)(&As[m_base + mq][ko]);
        half8 a1 = *(const half8*)(&As[m_base + 16 + mq][ko]);
        #pragma unroll
        for (int u = 0; u < 2; ++u) {
            acc[0][u] = __builtin_amdgcn_mfma_f32_16x16x32_f16(a0, wf[kk][u], acc[0][u], 0, 0, 0);
            acc[1][u] = __builtin_amdgcn_mfma_f32_16x16x32_f16(a1, wf[kk][u], acc[1][u], 0, 0, 0);
        }
    }

    #pragma unroll
    for (int t = 0; t < 2; ++t)
        #pragma unroll
        for (int u = 0; u < 2; ++u) {
            int c32 = u * 16 + mq;
            if (c32 < OPB) {
                float bvv = bo[bus * OPB + c32];
                #pragma unroll
                for (int r = 0; r < 4; ++r) {
                    int rowg = rb + m_base + t * 16 + q * 4 + r;
                    out[(size_t)rowg * OUTD + bus * OPB + c32] = acc[t][u][r] + bvv;
                }
            }
        }
}

// ---------------------------------------------------------------------------
extern "C" void kernel_launch(void* const* d_in, const int* in_sizes, int n_in,
                              void* d_out, int out_size, void* d_ws, size_t ws_size,
                              hipStream_t stream) {
    const float* x  = (const float*)d_in[0];
    const float* W0 = (const float*)d_in[1];
    const float* b0 = (const float*)d_in[2];
    const float* W1 = (const float*)d_in[3];
    const float* b1 = (const float*)d_in[4];
    const float* W2 = (const float*)d_in[5];
    const float* b2 = (const float*)d_in[6];
    const float* W3 = (const float*)d_in[7];
    const float* b3 = (const float*)d_in[8];
    const float* Wo = (const float*)d_in[9];
    const float* bo = (const float*)d_in[10];
    float* out = (float*)d_out;

    // ws layout: whpF 7,077,888 B | w0F 393,216 | woF 393,216 | hA 50,331,648 | hB 50,331,648
    char* ws = (char*)d_ws;
    unsigned short* whpF = (unsigned short*)(ws);
    unsigned short* w0F  = (unsigned short*)(ws + 7077888);
    unsigned short* woF  = (unsigned short*)(ws + 7471104);
    unsigned short* hA   = (unsigned short*)(ws + 7864320);
    unsigned short* hB   = (unsigned short*)(ws + 58195968);

    const int PACK_TOTAL = 3 * NB * 12288 + NB * 2048 + NB * 2048; // 3,932,160
    pack_weights<<<dim3(PACK_TOTAL / 256), dim3(256), 0, stream>>>(
        W0, W1, W2, W3, Wo, whpF, w0F, woF);

    layer0_kernel<<<dim3(NB, 32), dim3(256), 0, stream>>>(x, w0F, b0, hA);
    mid_kernel<<<dim3(NB, 16), dim3(256), 0, stream>>>(hA, whpF,               b1, hB);
    mid_kernel<<<dim3(NB, 16), dim3(256), 0, stream>>>(hB, whpF + 1179648,     b2, hA);
    mid_kernel<<<dim3(NB, 16), dim3(256), 0, stream>>>(hA, whpF + 2 * 1179648, b3, hB);
    out_kernel<<<dim3(NB, 32), dim3(256), 0, stream>>>(hB, woF, bo, out);
}

// Round 2
// 775.180 us; speedup vs baseline: 1.0252x; 1.0252x over previous
//
#include <hip/hip_runtime.h>

#define NB    96
#define HID   6144
#define INSZ  2048
#define FPB   21
#define OPB   21
#define OUTD  2016
#define BATCH 4096
#define NEG   0.01f

typedef _Float16 half8 __attribute__((ext_vector_type(8)));
typedef float floatx4 __attribute__((ext_vector_type(4)));

__device__ __forceinline__ unsigned short f2h_bits(float f) {
    union { _Float16 h; unsigned short u; } v;
    v.h = (_Float16)f;
    return v.u;
}

// ---------------------------------------------------------------------------
// Pack masked weights into FRAGMENT-MAJOR f16 layouts so each wave's 16B
// B-fragment load is one fully-coalesced 1KB transaction.
//  whpF: [3][96][kk=6][u=4][lane=64][j=8]   element (col=u*16+(lane&15),
//         k=kk*32+(lane>>4)*8+j) of the gathered [64][192] per-bus block
//  w0F : [96][u=4][lane=64][j=8]            k = (lane>>4)*8+j  (K=32)
//  woF : [96][kk=2][u=2][lane=64][j=8]      out-row=u*16+(lane&15), K=64
// ---------------------------------------------------------------------------
__global__ __launch_bounds__(256) void pack_weights(
    const float* __restrict__ W0, const float* __restrict__ W1,
    const float* __restrict__ W2, const float* __restrict__ W3,
    const float* __restrict__ Wo,
    unsigned short* __restrict__ whpF,
    unsigned short* __restrict__ w0F,
    unsigned short* __restrict__ woF)
{
    const int NH = 3 * NB * 12288;   // 3538944
    const int N0 = NB * 2048;        // 196608
    const int NO = NB * 2048;        // 196608
    int idx = blockIdx.x * 256 + threadIdx.x;
    if (idx < NH) {
        int e = idx;
        int l = e / 1179648;
        int r = e - l * 1179648;
        int bus = r / 12288;
        int r1 = r - bus * 12288;
        int kk = r1 >> 11;
        int r2 = r1 & 2047;
        int u = r2 >> 9;
        int r3 = r2 & 511;
        int lane = r3 >> 3, j = r3 & 7;
        int mq = lane & 15, q = lane >> 4;
        int col = u * 16 + mq;
        int k = kk * 32 + q * 8 + j;
        int src_b = (bus + 95 + (k >> 6)) % NB;
        const float* W = (l == 0) ? W1 : (l == 1) ? W2 : W3;
        float v = W[(size_t)(bus * 64 + col) * HID + src_b * 64 + (k & 63)];
        whpF[e] = f2h_bits(v);
    } else if (idx < NH + N0) {
        int e = idx - NH;
        int bus = e >> 11;
        int r = e & 2047;
        int u = r >> 9;
        int r2 = r & 511;
        int lane = r2 >> 3, j = r2 & 7;
        int mq = lane & 15, q = lane >> 4;
        int col = u * 16 + mq;
        int k = q * 8 + j;
        float v = 0.f;
        if (k < FPB)      v = W0[(size_t)(bus * 64 + col) * INSZ + bus * FPB + k];
        else if (k < 30)  v = W0[(size_t)(bus * 64 + col) * INSZ + (INSZ - 9) + (k - FPB)];
        w0F[e] = f2h_bits(v);
    } else if (idx < NH + N0 + NO) {
        int e = idx - NH - N0;
        int bus = e >> 11;
        int r = e & 2047;
        int kk = r >> 10;
        int r2 = r & 1023;
        int u = r2 >> 9;
        int r3 = r2 & 511;
        int lane = r3 >> 3, j = r3 & 7;
        int mq = lane & 15, q = lane >> 4;
        int row32 = u * 16 + mq;
        int k = kk * 32 + q * 8 + j;
        float v = 0.f;
        if (row32 < OPB)
            v = Wo[(size_t)(bus * OPB + row32) * HID + bus * 64 + k];
        woF[e] = f2h_bits(v);
    }
}

// ---------------------------------------------------------------------------
// Async A-chunk prefetch: 64 rows x 192 cols gathered into granule-swizzled
// LDS: granule g holds (row=g/24, kg=(g%24 - row%24) mod 24) -> compute reads
// land 2-way bank aliased (free). global_load_lds needs dest = uniform base +
// lane*16, which this satisfies by construction.
// ---------------------------------------------------------------------------
__device__ __forceinline__ void mid_prefetch(
    const unsigned short* __restrict__ hin, unsigned short* AsBuf,
    int tid, int gbase_row, int cb0, int cb1, int cb2)
{
    #pragma unroll
    for (int i = 0; i < 6; ++i) {
        int g = i * 256 + tid;
        int row = g / 24;
        int j = g - row * 24;
        int kg = j - (row % 24);
        kg += (kg < 0) ? 24 : 0;
        const unsigned short* src = hin + (size_t)(gbase_row + row) * HID
                                  + (kg < 8 ? cb0 : (kg < 16 ? cb1 : cb2)) + (kg & 7) * 8;
        __builtin_amdgcn_global_load_lds(
            (const __attribute__((address_space(1))) unsigned int*)src,
            (__attribute__((address_space(3))) unsigned int*)(AsBuf + (size_t)(i * 256 + (tid & ~63)) * 8),
            16, 0, 0);
    }
}

// ---------------------------------------------------------------------------
// Middle layers: per-bus GEMM M=4096,N=64,K=192. Block: 256 thr, M=256 in
// 4 chunks of 64 rows, double-buffered async staging. W frags in registers.
//
// XCD-aware remap: XCD k owns buses [12k,12k+12) so the ring-shared activation
// column slices stay in one (non-coherent) per-XCD L2. 1536 % 8 == 0.
//
// Counted-vmcnt pipeline (this round): __syncthreads() per chunk drained
// vmcnt(0) — waiting on 16 fresh stores + the just-issued next-chunk prefetch.
// Replaced with raw s_barrier + per-wave counted s_waitcnt so prefetch and
// stores stay in flight across barriers. Per-wave VMEM queue at the iter-c
// wait (need chunk-c loads done): newer ops = S(c-1)[16] + L(c+1)[6]:
//   c=0: vmcnt(6)   c=1,2: vmcnt(22)   c=3: vmcnt(16)
// Hazards: buffer overwrite guarded by end-of-iter barrier (all waves done
// reading buf before next prefetch into it); compute-ready guarded by
// wait+barrier pair. Counts only over-wait if extra VMEM (spills) appear.
// ---------------------------------------------------------------------------
__global__ __launch_bounds__(256) void mid_kernel(
    const unsigned short* __restrict__ hin,
    const unsigned short* __restrict__ WpF,   // fragment-major, this layer
    const float* __restrict__ bias,
    unsigned short* __restrict__ hout)
{
    __shared__ unsigned short AsF[2][1536 * 8];   // 2 x 24 KB
    const int lin = blockIdx.y * NB + blockIdx.x;
    const int xcd = lin & 7;
    const int idx = lin >> 3;
    const int bus = xcd * 12 + (idx % 12);
    const int rowblk = (idx / 12) * 256;
    const int tid = threadIdx.x;
    const int lane = tid & 63, wid = tid >> 6;
    const int mq = lane & 15, q = lane >> 4;
    const int cb0 = ((bus + 95) % NB) * 64;
    const int cb1 = bus * 64;
    const int cb2 = ((bus + 1) % NB) * 64;

    half8 bfr[6][4];
    #pragma unroll
    for (int kk = 0; kk < 6; ++kk)
        #pragma unroll
        for (int u = 0; u < 4; ++u)
            bfr[kk][u] = *(const half8*)(WpF + (size_t)(((bus * 6 + kk) * 4 + u) * 512) + lane * 8);

    float bv[4];
    #pragma unroll
    for (int u = 0; u < 4; ++u) bv[u] = bias[bus * 64 + u * 16 + mq];

    mid_prefetch(hin, &AsF[0][0], tid, rowblk, cb0, cb1, cb2);

    const int row = wid * 16 + mq;       // row within chunk, 0..63
    const int r24 = row % 24;
    const int qr = q + r24;

    #pragma unroll
    for (int c = 0; c < 4; ++c) {
        int buf = c & 1;
        if (c < 3)
            mid_prefetch(hin, &AsF[buf ^ 1][0], tid, rowblk + (c + 1) * 64, cb0, cb1, cb2);

        // wait for this wave's chunk-c loads only (counted), then sync all waves
        if (c == 0)      asm volatile("s_waitcnt vmcnt(6)"  ::: "memory");
        else if (c == 3) asm volatile("s_waitcnt vmcnt(16)" ::: "memory");
        else             asm volatile("s_waitcnt vmcnt(22)" ::: "memory");
        __builtin_amdgcn_s_barrier();

        floatx4 acc[4];
        #pragma unroll
        for (int u = 0; u < 4; ++u) acc[u] = (floatx4){0.f, 0.f, 0.f, 0.f};

        #pragma unroll
        for (int kk = 0; kk < 6; ++kk) {
            int vv = 4 * kk + qr;
            if (vv >= 24) vv -= 24;
            half8 a = *(const half8*)(&AsF[buf][(row * 24 + vv) * 8]);
            #pragma unroll
            for (int u = 0; u < 4; ++u)
                acc[u] = __builtin_amdgcn_mfma_f32_16x16x32_f16(a, bfr[kk][u], acc[u], 0, 0, 0);
        }

        int orow = rowblk + c * 64 + wid * 16 + q * 4;
        #pragma unroll
        for (int u = 0; u < 4; ++u) {
            int colg = bus * 64 + u * 16 + mq;
            #pragma unroll
            for (int r = 0; r < 4; ++r) {
                float v = acc[u][r] + bv[u];
                v = (v >= 0.f) ? v : NEG * v;
                hout[(size_t)(orow + r) * HID + colg] = f2h_bits(v);
            }
        }
        // all waves done reading AsF[buf] before next iter's prefetch overwrites it
        if (c < 3) __builtin_amdgcn_s_barrier();
    }
}

// ---------------------------------------------------------------------------
// Fused layer-3 + output: identical mid-layer GEMM, but instead of writing h3
// to HBM (50 MB) and re-reading it (50 MB) in a separate out_kernel, each
// chunk's post-activation values take a per-wave LDS round-trip (transpose to
// MFMA-A layout) and feed the K=64 out-GEMM directly: Mo masks bus b's
// outputs to bus b's own hidden block, which is exactly what this block holds.
// Scratch lives in the just-consumed, per-wave-disjoint 6144 B region of
// AsF[buf] (wave w computes/reads only rows w*16..w*16+15 = bytes
// [w*6144, w*6144+6144)), so no extra LDS and no extra barrier.
// vmcnt counts: stores/chunk = 8 f32 -> c=0: 6, c=1,2: 14, c=3: 8.
// ---------------------------------------------------------------------------
__global__ __launch_bounds__(256) void mid_out_kernel(
    const unsigned short* __restrict__ hin,
    const unsigned short* __restrict__ WpF,   // layer-3 frags
    const float* __restrict__ bias,           // b3
    const unsigned short* __restrict__ woF,
    const float* __restrict__ bo,
    float* __restrict__ out)
{
    __shared__ unsigned short AsF[2][1536 * 8];   // 2 x 24 KB
    const int lin = blockIdx.y * NB + blockIdx.x;
    const int xcd = lin & 7;
    const int idx = lin >> 3;
    const int bus = xcd * 12 + (idx % 12);
    const int rowblk = (idx / 12) * 256;
    const int tid = threadIdx.x;
    const int lane = tid & 63, wid = tid >> 6;
    const int mq = lane & 15, q = lane >> 4;
    const int cb0 = ((bus + 95) % NB) * 64;
    const int cb1 = bus * 64;
    const int cb2 = ((bus + 1) % NB) * 64;

    half8 bfr[6][4];
    #pragma unroll
    for (int kk = 0; kk < 6; ++kk)
        #pragma unroll
        for (int u = 0; u < 4; ++u)
            bfr[kk][u] = *(const half8*)(WpF + (size_t)(((bus * 6 + kk) * 4 + u) * 512) + lane * 8);

    half8 wf[2][2];
    #pragma unroll
    for (int kk = 0; kk < 2; ++kk)
        #pragma unroll
        for (int u = 0; u < 2; ++u)
            wf[kk][u] = *(const half8*)(woF + (size_t)(((bus * 2 + kk) * 2 + u) * 512) + lane * 8);

    float bv[4];
    #pragma unroll
    for (int u = 0; u < 4; ++u) bv[u] = bias[bus * 64 + u * 16 + mq];

    float bvo[2];
    #pragma unroll
    for (int u = 0; u < 2; ++u) {
        int c32 = u * 16 + mq;
        bvo[u] = (c32 < OPB) ? bo[bus * OPB + c32] : 0.f;
    }

    mid_prefetch(hin, &AsF[0][0], tid, rowblk, cb0, cb1, cb2);

    const int row = wid * 16 + mq;
    const int r24 = row % 24;
    const int qr = q + r24;

    #pragma unroll
    for (int c = 0; c < 4; ++c) {
        int buf = c & 1;
        if (c < 3)
            mid_prefetch(hin, &AsF[buf ^ 1][0], tid, rowblk + (c + 1) * 64, cb0, cb1, cb2);

        if (c == 0)      asm volatile("s_waitcnt vmcnt(6)"  ::: "memory");
        else if (c == 3) asm volatile("s_waitcnt vmcnt(8)"  ::: "memory");
        else             asm volatile("s_waitcnt vmcnt(14)" ::: "memory");
        __builtin_amdgcn_s_barrier();

        floatx4 acc[4];
        #pragma unroll
        for (int u = 0; u < 4; ++u) acc[u] = (floatx4){0.f, 0.f, 0.f, 0.f};

        #pragma unroll
        for (int kk = 0; kk < 6; ++kk) {
            int vv = 4 * kk + qr;
            if (vv >= 24) vv -= 24;
            half8 a = *(const half8*)(&AsF[buf][(row * 24 + vv) * 8]);
            #pragma unroll
            for (int u = 0; u < 4; ++u)
                acc[u] = __builtin_amdgcn_mfma_f32_16x16x32_f16(a, bfr[kk][u], acc[u], 0, 0, 0);
        }

        // epilogue: bias + leaky -> f16 into per-wave scratch (rows 0..15 of
        // this wave's 16-row group, padded row stride 80 shorts for alignment)
        unsigned short* myscr = &AsF[buf][wid * 3072];
        #pragma unroll
        for (int u = 0; u < 4; ++u) {
            #pragma unroll
            for (int r = 0; r < 4; ++r) {
                float v = acc[u][r] + bv[u];
                v = (v >= 0.f) ? v : NEG * v;
                myscr[(q * 4 + r) * 80 + u * 16 + mq] = f2h_bits(v);
            }
        }

        floatx4 acco[2];
        #pragma unroll
        for (int u = 0; u < 2; ++u) acco[u] = (floatx4){0.f, 0.f, 0.f, 0.f};

        #pragma unroll
        for (int kk = 0; kk < 2; ++kk) {
            half8 a = *(const half8*)(myscr + mq * 80 + kk * 32 + q * 8);
            #pragma unroll
            for (int u = 0; u < 2; ++u)
                acco[u] = __builtin_amdgcn_mfma_f32_16x16x32_f16(a, wf[kk][u], acco[u], 0, 0, 0);
        }

        int orow = rowblk + c * 64 + wid * 16 + q * 4;
        #pragma unroll
        for (int u = 0; u < 2; ++u) {
            int c32 = u * 16 + mq;
            if (c32 < OPB) {
                #pragma unroll
                for (int r = 0; r < 4; ++r)
                    out[(size_t)(orow + r) * OUTD + bus * OPB + c32] = acco[u][r] + bvo[u];
            }
        }

        if (c < 3) __builtin_amdgcn_s_barrier();
    }
}

// ---------------------------------------------------------------------------
// Layer 0: per-bus GEMM M=4096,N=64,K=32 (30 real). W frags in registers,
// LDS only for gathered f32->f16 A tile (10 KB -> high occupancy).
// ---------------------------------------------------------------------------
__global__ __launch_bounds__(256) void layer0_kernel(
    const float* __restrict__ x,
    const unsigned short* __restrict__ w0F,
    const float* __restrict__ b0,
    unsigned short* __restrict__ hout)
{
    __shared__ unsigned short As[128][40];
    int bus = blockIdx.x, rb = blockIdx.y * 128, tid = threadIdx.x;
    int lane = tid & 63, wid = tid >> 6, mq = lane & 15, q = lane >> 4;

    half8 b0f[4];
    #pragma unroll
    for (int u = 0; u < 4; ++u)
        b0f[u] = *(const half8*)(w0F + (size_t)(bus * 4 + u) * 512 + lane * 8);

    #pragma unroll
    for (int i = 0; i < 16; ++i) {
        int g = i * 256 + tid;
        int row = g >> 5, k = g & 31;
        float v = 0.f;
        if (k < FPB)      v = x[(size_t)(rb + row) * INSZ + bus * FPB + k];
        else if (k < 30)  v = x[(size_t)(rb + row) * INSZ + (INSZ - 9) + (k - FPB)];
        As[row][k] = f2h_bits(v);
    }
    __syncthreads();

    int m_base = wid * 32;
    floatx4 acc[2][4];
    #pragma unroll
    for (int t = 0; t < 2; ++t)
        #pragma unroll
        for (int u = 0; u < 4; ++u)
            acc[t][u] = (floatx4){0.f, 0.f, 0.f, 0.f};

    half8 a0 = *(const half8*)(&As[m_base + mq][q * 8]);
    half8 a1 = *(const half8*)(&As[m_base + 16 + mq][q * 8]);
    #pragma unroll
    for (int u = 0; u < 4; ++u) {
        acc[0][u] = __builtin_amdgcn_mfma_f32_16x16x32_f16(a0, b0f[u], acc[0][u], 0, 0, 0);
        acc[1][u] = __builtin_amdgcn_mfma_f32_16x16x32_f16(a1, b0f[u], acc[1][u], 0, 0, 0);
    }

    #pragma unroll
    for (int t = 0; t < 2; ++t)
        #pragma unroll
        for (int u = 0; u < 4; ++u) {
            int col = bus * 64 + u * 16 + mq;
            float bvv = b0[col];
            #pragma unroll
            for (int r = 0; r < 4; ++r) {
                int rowg = rb + m_base + t * 16 + q * 4 + r;
                float v = acc[t][u][r] + bvv;
                v = (v >= 0.f) ? v : NEG * v;
                hout[(size_t)rowg * HID + col] = f2h_bits(v);
            }
        }
}

// ---------------------------------------------------------------------------
extern "C" void kernel_launch(void* const* d_in, const int* in_sizes, int n_in,
                              void* d_out, int out_size, void* d_ws, size_t ws_size,
                              hipStream_t stream) {
    const float* x  = (const float*)d_in[0];
    const float* W0 = (const float*)d_in[1];
    const float* b0 = (const float*)d_in[2];
    const float* W1 = (const float*)d_in[3];
    const float* b1 = (const float*)d_in[4];
    const float* W2 = (const float*)d_in[5];
    const float* b2 = (const float*)d_in[6];
    const float* W3 = (const float*)d_in[7];
    const float* b3 = (const float*)d_in[8];
    const float* Wo = (const float*)d_in[9];
    const float* bo = (const float*)d_in[10];
    float* out = (float*)d_out;

    // ws layout: whpF 7,077,888 B | w0F 393,216 | woF 393,216 | hA 50,331,648 | hB 50,331,648
    char* ws = (char*)d_ws;
    unsigned short* whpF = (unsigned short*)(ws);
    unsigned short* w0F  = (unsigned short*)(ws + 7077888);
    unsigned short* woF  = (unsigned short*)(ws + 7471104);
    unsigned short* hA   = (unsigned short*)(ws + 7864320);
    unsigned short* hB   = (unsigned short*)(ws + 58195968);

    const int PACK_TOTAL = 3 * NB * 12288 + NB * 2048 + NB * 2048; // 3,932,160
    pack_weights<<<dim3(PACK_TOTAL / 256), dim3(256), 0, stream>>>(
        W0, W1, W2, W3, Wo, whpF, w0F, woF);

    layer0_kernel<<<dim3(NB, 32), dim3(256), 0, stream>>>(x, w0F, b0, hA);
    mid_kernel<<<dim3(NB, 16), dim3(256), 0, stream>>>(hA, whpF,           b1, hB);
    mid_kernel<<<dim3(NB, 16), dim3(256), 0, stream>>>(hB, whpF + 1179648, b2, hA);
    mid_out_kernel<<<dim3(NB, 16), dim3(256), 0, stream>>>(
        hA, whpF + 2 * 1179648, b3, woF, bo, out);
}